// Round 7
// baseline (335.845 us; speedup 1.0000x reference)
//
#include <hip/hip_runtime.h>

#define B_ 16
#define D_ 128
#define L_ 8192
#define M_ 128
#define NCHUNK 32
#define LT 256
#define SL 64
#define PHI_SCALE 0.08838834764831845f

typedef unsigned short ushort_t;
typedef ushort_t ushort8 __attribute__((ext_vector_type(8)));
typedef ushort_t ushort4v __attribute__((ext_vector_type(4)));
typedef float float4v __attribute__((ext_vector_type(4)));
typedef __bf16 bf16x8 __attribute__((ext_vector_type(8)));

__device__ __forceinline__ ushort_t f2bf(float f) {
    unsigned int u = __builtin_bit_cast(unsigned int, f);
    unsigned int r = u + 0x7FFFu + ((u >> 16) & 1u);   // RTNE
    return (ushort_t)(r >> 16);
}

__device__ __forceinline__ float4v mfma16(ushort8 a, ushort8 b, float4v c) {
    return __builtin_amdgcn_mfma_f32_16x16x32_bf16(
        __builtin_bit_cast(bf16x8, a), __builtin_bit_cast(bf16x8, b), c, 0, 0, 0);
}

// Stage F (D x M) into LDS as GEMM B-fragment layout: blocks [kt 0..3][nt 0..7][lane64][j 0..7]
__device__ __forceinline__ void stage_features(const float* __restrict__ features,
                                               ushort_t* FB, int tid) {
#pragma unroll
    for (int it = 0; it < 8; ++it) {
        int bid = tid + it * 256;            // 0..2047
        int cb = bid & 15;
        int qb = (bid >> 4) & 3;
        int nt = (bid >> 6) & 7;
        int kt = bid >> 9;
        int m  = nt * 16 + cb;
        int d0 = kt * 32 + qb * 8;
        const float* fp = features + d0 * M_ + m;
        ushort8 u;
#pragma unroll
        for (int j = 0; j < 8; ++j) u[j] = f2bf(fp[j * M_]);
        *(ushort8*)(FB + bid * 8) = u;
    }
}

// ---- raw-f32 load helpers (issue-only; convert at use) ----
__device__ __forceinline__ void loadK(const float* kcol, int ls, int lrel, int qa,
                                      float (&fk)[4][8]) {
#pragma unroll
    for (int kt = 0; kt < 4; ++kt)
#pragma unroll
        for (int j = 0; j < 8; ++j)
            fk[kt][j] = kcol[(size_t)(kt * 32 + qa * 8 + j) * L_ + ls + lrel];
}

// V^T A-frag raw loads: lane (qa,ra) of wave w reads 8 consecutive l for its v-row.
__device__ __forceinline__ void loadV2(const float* vrow0, const float* vrow1, int ls, int qa,
                                       float4v (&vr)[2][2][2]) {
#pragma unroll
    for (int kt2 = 0; kt2 < 2; ++kt2) {
        const float* p0 = vrow0 + ls + kt2 * 32 + qa * 8;
        const float* p1 = vrow1 + ls + kt2 * 32 + qa * 8;
        vr[0][kt2][0] = *(const float4v*)p0;
        vr[0][kt2][1] = *(const float4v*)(p0 + 4);
        vr[1][kt2][0] = *(const float4v*)p1;
        vr[1][kt2][1] = *(const float4v*)(p1 + 4);
    }
}

// Kernel A: per (chunk,b): phi_k = relu(K^T F)*s ; kv^T[v][m] += V^T phi ; ksum partials.
// V consumed as in-register A-frags (no LDS staging) -> LDS = FB 32K + PB 16K = 48KB
// -> 3 blocks/CU (12 waves). Wave w owns v-rows [32w, 32w+32).
__global__ __launch_bounds__(256, 3) void kernelA(const float* __restrict__ keys,
                                                  const float* __restrict__ values,
                                                  const float* __restrict__ features,
                                                  float* __restrict__ kvp,
                                                  float* __restrict__ ksum_p) {
    __shared__ ushort_t FB[16384];  // 32 KB : F B-frags
    __shared__ ushort_t PB[8192];   // 16 KB : phi B-frags (B[k=l][n=m])

    const int tid = threadIdx.x;
    const int chunk = blockIdx.x, b = blockIdx.y;
    const int w = tid >> 6, lane = tid & 63;
    const int qa = lane >> 4, ra = lane & 15;
    const int l0 = chunk * LT;
    const int lrel = w * 16 + ra;

    const float* kcol  = keys + (size_t)b * D_ * L_;
    const float* vrow0 = values + ((size_t)(b * D_ + w * 32 + ra)) * L_;
    const float* vrow1 = values + ((size_t)(b * D_ + w * 32 + 16 + ra)) * L_;

    // ---- prologue: s0 V + K raw loads, then F staging
    float4v vr[2][2][2];   // [t][kt2][half]
    float   fk[4][8];
    loadV2(vrow0, vrow1, l0, qa, vr);
    loadK(kcol, l0, lrel, qa, fk);

    stage_features(features, FB, tid);

    float4v acc2[2][8];    // kv^T C-frags: [t = v-16-tile][nt = m-tile]
    float   ksum_acc[8];
#pragma unroll
    for (int t = 0; t < 2; ++t)
#pragma unroll
        for (int nt = 0; nt < 8; ++nt) acc2[t][nt] = (float4v){0.f, 0.f, 0.f, 0.f};
#pragma unroll
    for (int nt = 0; nt < 8; ++nt) ksum_acc[nt] = 0.f;

#pragma unroll
    for (int s = 0; s < 4; ++s) {
        const int ls = l0 + s * SL;
        __syncthreads();  // prev GEMM2 reads of PB done; (s=0: FB visible)

        // ---- convert V (A-frags for GEMM2), consumes vr
        ushort8 av[2][2];
#pragma unroll
        for (int t = 0; t < 2; ++t)
#pragma unroll
            for (int kt2 = 0; kt2 < 2; ++kt2) {
                float4v a0 = vr[t][kt2][0], a1 = vr[t][kt2][1];
                ushort8 u;
                u[0] = f2bf(a0.x); u[1] = f2bf(a0.y); u[2] = f2bf(a0.z); u[3] = f2bf(a0.w);
                u[4] = f2bf(a1.x); u[5] = f2bf(a1.y); u[6] = f2bf(a1.z); u[7] = f2bf(a1.w);
                av[t][kt2] = u;
            }
        // ---- convert K (A-frags for GEMM1), consumes fk
        ushort8 af[4];
#pragma unroll
        for (int kt = 0; kt < 4; ++kt) {
            ushort8 a;
#pragma unroll
            for (int j = 0; j < 8; ++j) a[j] = f2bf(fk[kt][j]);
            af[kt] = a;
        }
        // ---- prefetch next s-iter (in flight through GEMM1+epilogue)
        if (s < 3) {
            loadV2(vrow0, vrow1, ls + SL, qa, vr);
            loadK(kcol, ls + SL, lrel, qa, fk);
        }

        // ---- GEMM1: phi(64 x 128) = K_sub^T @ F; wave w owns l-rows [w*16, w*16+16)
        float4v acc1[8];
#pragma unroll
        for (int nt = 0; nt < 8; ++nt) acc1[nt] = (float4v){0.f, 0.f, 0.f, 0.f};
#pragma unroll
        for (int kt = 0; kt < 4; ++kt)
#pragma unroll
            for (int nt = 0; nt < 8; ++nt)
                acc1[nt] = mfma16(af[kt], *(const ushort8*)(FB + ((kt * 8 + nt) * 64 + lane) * 8),
                                  acc1[nt]);

        // ---- epilogue: relu*scale, ksum, write phi into PB as B-frag [k=l][n=m]
        {
            const int qc = qa, cc = ra;
            const int kt2w = w >> 1;
            const int qb2  = (w & 1) * 2 + (qc >> 1);
            const int jb   = (qc & 1) * 4;
#pragma unroll
            for (int nt = 0; nt < 8; ++nt) {
                float4v p = acc1[nt];
                p.x = fmaxf(p.x, 0.f) * PHI_SCALE;
                p.y = fmaxf(p.y, 0.f) * PHI_SCALE;
                p.z = fmaxf(p.z, 0.f) * PHI_SCALE;
                p.w = fmaxf(p.w, 0.f) * PHI_SCALE;
                ksum_acc[nt] += p.x + p.y + p.z + p.w;
                ushort4v u4 = {f2bf(p.x), f2bf(p.y), f2bf(p.z), f2bf(p.w)};
                *(ushort4v*)(PB + (((kt2w * 8 + nt) * 64 + qb2 * 16 + cc) * 8 + jb)) = u4;
            }
        }
        __syncthreads();  // PB visible

        // ---- GEMM2: kv^T[v][m] += V^T (32v x 64l) @ phi (64l x 128m), per-wave v-rows
#pragma unroll
        for (int kt2 = 0; kt2 < 2; ++kt2)
#pragma unroll
            for (int nt = 0; nt < 8; ++nt) {
                ushort8 bb = *(const ushort8*)(PB + ((kt2 * 8 + nt) * 64 + lane) * 8);
                acc2[0][nt] = mfma16(av[0][kt2], bb, acc2[0][nt]);
                acc2[1][nt] = mfma16(av[1][kt2], bb, acc2[1][nt]);
            }
    }

    // ---- store kv^T partials (f32, [v][m] row-major) and ksum partials
    float* kvpb = kvp + ((size_t)(b * NCHUNK + chunk)) * (M_ * D_);
    const int qc = lane >> 4, cc = lane & 15;
#pragma unroll
    for (int t = 0; t < 2; ++t)
#pragma unroll
        for (int nt = 0; nt < 8; ++nt) {
            float4v p = acc2[t][nt];
            int v0 = w * 32 + t * 16 + qc * 4;
            int m  = nt * 16 + cc;
            kvpb[(v0 + 0) * M_ + m] = p.x;
            kvpb[(v0 + 1) * M_ + m] = p.y;
            kvpb[(v0 + 2) * M_ + m] = p.z;
            kvpb[(v0 + 3) * M_ + m] = p.w;
        }
    float* ksb = ksum_p + ((size_t)((b * NCHUNK + chunk) * 4 + w)) * M_;
#pragma unroll
    for (int nt = 0; nt < 8; ++nt) {
        float sv = ksum_acc[nt];
        sv += __shfl_xor(sv, 16);
        sv += __shfl_xor(sv, 32);
        if (qc == 0) ksb[nt * 16 + cc] = sv;
    }
}

// Kernel R: reduce 32 chunk-partials (kvp is [v][m] f32) -> kv_final bf16 B-frag blocks
// [kt][nt][lane][j] + ksum_final f32 [b][128]. Reads are contiguous float4s now.
__global__ __launch_bounds__(256) void kernelR(const float* __restrict__ kvp,
                                               const float* __restrict__ ksum_p,
                                               ushort_t* __restrict__ kv_final,
                                               float* __restrict__ ksum_final) {
    if (blockIdx.x < 256) {
        int h = blockIdx.x >> 7;                         // j-half 0/1
        int t = (blockIdx.x & 127) * 256 + threadIdx.x;  // 0..32767 (b*2048 + bid)
        int b = t >> 11, bid = t & 2047;
        int cb = bid & 15, qb = (bid >> 4) & 3, nt = (bid >> 6) & 7, kt = bid >> 9;
        int v  = nt * 16 + cb;
        int m0 = kt * 32 + qb * 8 + h * 4;
        const float* base = kvp + ((size_t)b * NCHUNK) * (M_ * D_) + v * M_ + m0;
        float s0 = 0.f, s1 = 0.f, s2 = 0.f, s3 = 0.f;
#pragma unroll 4
        for (int c = 0; c < NCHUNK; ++c) {
            float4v u = *(const float4v*)(base + (size_t)c * (M_ * D_));
            s0 += u.x; s1 += u.y; s2 += u.z; s3 += u.w;
        }
        ushort4v u = {f2bf(s0), f2bf(s1), f2bf(s2), f2bf(s3)};
        *(ushort4v*)(kv_final + (size_t)t * 8 + h * 4) = u;
    } else {
        int t2 = (blockIdx.x - 256) * 256 + threadIdx.x;  // 0..2047
        int b = t2 >> 7, m = t2 & 127;
        const float* p = ksum_p + ((size_t)b * NCHUNK) * 4 * M_ + m;
        float sacc = 0.f;
#pragma unroll 8
        for (int cw = 0; cw < NCHUNK * 4; ++cw) sacc += p[cw * M_];
        ksum_final[t2] = sacc;
    }
}

// Kernel QC (round-2 form, best measured): phi_q = relu(Q^T F)*s ; out = (phi_q @ kv)/(phi_q . ksum)
// LDS = 32+32+8 = 72 KB -> 2 blocks/CU. No barriers in the s-loop (PQA per-wave-private).
__global__ __launch_bounds__(256, 2) void kernelQC(const float* __restrict__ queries,
                                                   const float* __restrict__ features,
                                                   const ushort_t* __restrict__ kv_final,
                                                   const float* __restrict__ ksum_final,
                                                   float* __restrict__ out) {
    __shared__ ushort_t FB[16384];   // 32 KB : F B-frags
    __shared__ ushort_t KVB[16384];  // 32 KB : kv B-frags (B[k=m][n=v])
    __shared__ ushort_t PQA[4096];   //  8 KB : phi_q A-frags, per-wave halves

    const int tid = threadIdx.x;
    const int chunk = blockIdx.x, b = blockIdx.y;
    const int w = tid >> 6, lane = tid & 63;
    const int qa = lane >> 4, ra = lane & 15;
    const int qc = qa, cc = ra;
    const int lrel = w * 16 + ra;

    // ---- issue s=0 Q loads first (raw f32)
    const float* qbase = queries + (size_t)b * D_ * L_;
    float fq[4][8];
#pragma unroll
    for (int kt = 0; kt < 4; ++kt)
#pragma unroll
        for (int j = 0; j < 8; ++j)
            fq[kt][j] = qbase[(size_t)(kt * 32 + qa * 8 + j) * L_ + chunk * LT + lrel];

    stage_features(features, FB, tid);
#pragma unroll
    for (int it = 0; it < 8; ++it) {
        int bid = tid + it * 256;  // 0..2047
        *(ushort8*)(KVB + bid * 8) =
            *(const ushort8*)(kv_final + ((size_t)b * 2048 + bid) * 8);
    }
    float ks[8];
#pragma unroll
    for (int nt = 0; nt < 8; ++nt) ks[nt] = ksum_final[b * M_ + nt * 16 + ra];
    __syncthreads();

#pragma unroll
    for (int s = 0; s < 4; ++s) {
        const int ls = chunk * LT + s * SL;

        // ---- convert current Q (consumes fq)
        ushort8 af[4];
#pragma unroll
        for (int kt = 0; kt < 4; ++kt) {
            ushort8 a;
#pragma unroll
            for (int j = 0; j < 8; ++j) a[j] = f2bf(fq[kt][j]);
            af[kt] = a;
        }
        // ---- prefetch next s-iter's Q (no barriers here -> stays in flight)
        if (s < 3) {
#pragma unroll
            for (int kt = 0; kt < 4; ++kt)
#pragma unroll
                for (int j = 0; j < 8; ++j)
                    fq[kt][j] = qbase[(size_t)(kt * 32 + qa * 8 + j) * L_ + ls + SL + lrel];
        }

        // ---- GEMM1: phi_q(64 x 128) = Q_sub^T @ F
        float4v acc1[8];
#pragma unroll
        for (int nt = 0; nt < 8; ++nt) acc1[nt] = (float4v){0.f, 0.f, 0.f, 0.f};
#pragma unroll
        for (int kt = 0; kt < 4; ++kt)
#pragma unroll
            for (int nt = 0; nt < 8; ++nt)
                acc1[nt] = mfma16(af[kt], *(const ushort8*)(FB + ((kt * 8 + nt) * 64 + lane) * 8),
                                  acc1[nt]);

        // ---- relu*scale + f32 denominator dot (ksum in regs)
        float dp0 = 0.f, dp1 = 0.f, dp2 = 0.f, dp3 = 0.f;
#pragma unroll
        for (int nt = 0; nt < 8; ++nt) {
            float4v p = acc1[nt];
            p.x = fmaxf(p.x, 0.f) * PHI_SCALE;
            p.y = fmaxf(p.y, 0.f) * PHI_SCALE;
            p.z = fmaxf(p.z, 0.f) * PHI_SCALE;
            p.w = fmaxf(p.w, 0.f) * PHI_SCALE;
            dp0 += p.x * ks[nt]; dp1 += p.y * ks[nt];
            dp2 += p.z * ks[nt]; dp3 += p.w * ks[nt];
            acc1[nt] = p;
        }
#pragma unroll
        for (int off = 1; off < 16; off <<= 1) {
            dp0 += __shfl_xor(dp0, off);
            dp1 += __shfl_xor(dp1, off);
            dp2 += __shfl_xor(dp2, off);
            dp3 += __shfl_xor(dp3, off);
        }
        float i0 = 1.f / dp0, i1 = 1.f / dp1, i2 = 1.f / dp2, i3 = 1.f / dp3;

        // ---- GEMM2 in two m-halves through the 8KB per-wave PQA
        float4v acc[8];
#pragma unroll
        for (int nt = 0; nt < 8; ++nt) acc[nt] = (float4v){0.f, 0.f, 0.f, 0.f};
#pragma unroll
        for (int h = 0; h < 2; ++h) {
#pragma unroll
            for (int nt = 4 * h; nt < 4 * h + 4; ++nt) {
                float4v p = acc1[nt];
                int baseu = ((((nt >> 1) & 1) * 4 + w) * 64 +
                             ((nt & 1) * 2 + (cc >> 3)) * 16 + qc * 4) * 8 + (cc & 7);
                PQA[baseu +  0] = f2bf(p.x);
                PQA[baseu +  8] = f2bf(p.y);
                PQA[baseu + 16] = f2bf(p.z);
                PQA[baseu + 24] = f2bf(p.w);
            }
#pragma unroll
            for (int kt = 2 * h; kt < 2 * h + 2; ++kt) {
                ushort8 a = *(const ushort8*)(PQA + (((kt & 1) * 4 + w) * 64 + lane) * 8);
#pragma unroll
                for (int nt2 = 0; nt2 < 8; ++nt2)
                    acc[nt2] = mfma16(a, *(const ushort8*)(KVB + ((kt * 8 + nt2) * 64 + lane) * 8),
                                      acc[nt2]);
            }
        }

        // ---- scale by 1/denom and store
        const int lbase = ls + w * 16 + qc * 4;
#pragma unroll
        for (int nt = 0; nt < 8; ++nt) {
            float4v o = acc[nt];
            o.x *= i0; o.y *= i1; o.z *= i2; o.w *= i3;
            *(float4v*)(out + ((size_t)(b * D_ + nt * 16 + cc)) * L_ + lbase) = o;
        }
    }
}

extern "C" void kernel_launch(void* const* d_in, const int* in_sizes, int n_in,
                              void* d_out, int out_size, void* d_ws, size_t ws_size,
                              hipStream_t stream) {
    (void)in_sizes; (void)n_in; (void)out_size; (void)ws_size;
    const float* keys     = (const float*)d_in[0];
    const float* values   = (const float*)d_in[1];
    const float* queries  = (const float*)d_in[2];
    const float* features = (const float*)d_in[3];
    float* out = (float*)d_out;

    // workspace partition (total ~35.1 MB)
    char* ws = (char*)d_ws;
    float*    kvp        = (float*)ws;                        // 16*32*128*128*4 = 33,554,432
    float*    ksum_p     = (float*)(ws + 33554432);           // 16*32*4*128*4   =  1,048,576
    ushort_t* kv_final   = (ushort_t*)(ws + 34603008);        // 16*2048*8*2     =    524,288
    float*    ksum_final = (float*)(ws + 35127296);           // 16*128*4        =      8,192

    dim3 grid(NCHUNK, B_);
    kernelA<<<grid, 256, 0, stream>>>(keys, values, features, kvp, ksum_p);
    kernelR<<<264, 256, 0, stream>>>(kvp, ksum_p, kv_final, ksum_final);
    kernelQC<<<grid, 256, 0, stream>>>(queries, features, kv_final, ksum_final, out);
}

// Round 8
// 267.445 us; speedup vs baseline: 1.2558x; 1.2558x over previous
//
#include <hip/hip_runtime.h>

#define B_ 16
#define D_ 128
#define L_ 8192
#define M_ 128
#define NCHUNK 32
#define LT 256
#define SL 64
#define PHI_SCALE 0.08838834764831845f

typedef unsigned short ushort_t;
typedef ushort_t ushort8 __attribute__((ext_vector_type(8)));
typedef ushort_t ushort4v __attribute__((ext_vector_type(4)));
typedef float float4v __attribute__((ext_vector_type(4)));
typedef __bf16 bf16x8 __attribute__((ext_vector_type(8)));

// Barrier that drains ONLY LDS ops (lgkmcnt), leaving global prefetch loads in flight.
// __syncthreads() would emit s_waitcnt vmcnt(0) and drain the VMEM queue (the ~20% stall).
#define BAR_LDS() asm volatile("s_waitcnt lgkmcnt(0)\n\ts_barrier" ::: "memory")

__device__ __forceinline__ ushort_t f2bf(float f) {
    unsigned int u = __builtin_bit_cast(unsigned int, f);
    unsigned int r = u + 0x7FFFu + ((u >> 16) & 1u);   // RTNE
    return (ushort_t)(r >> 16);
}

__device__ __forceinline__ float4v mfma16(ushort8 a, ushort8 b, float4v c) {
    return __builtin_amdgcn_mfma_f32_16x16x32_bf16(
        __builtin_bit_cast(bf16x8, a), __builtin_bit_cast(bf16x8, b), c, 0, 0, 0);
}

// Stage F (D x M) into LDS as GEMM B-fragment layout: blocks [kt 0..3][nt 0..7][lane64][j 0..7]
__device__ __forceinline__ void stage_features(const float* __restrict__ features,
                                               ushort_t* FB, int tid) {
#pragma unroll
    for (int it = 0; it < 8; ++it) {
        int bid = tid + it * 256;            // 0..2047
        int cb = bid & 15;
        int qb = (bid >> 4) & 3;
        int nt = (bid >> 6) & 7;
        int kt = bid >> 9;
        int m  = nt * 16 + cb;
        int d0 = kt * 32 + qb * 8;
        const float* fp = features + d0 * M_ + m;
        ushort8 u;
#pragma unroll
        for (int j = 0; j < 8; ++j) u[j] = f2bf(fp[j * M_]);
        *(ushort8*)(FB + bid * 8) = u;
    }
}

// Kernel A: per (chunk,b): phi_k = relu(K^T F)*s ; kv_part[m][v] += phi^T V^T ; ksum partials
// LDS 64KB -> 2 blocks/CU. In-loop barriers drain lgkmcnt only, so the depth-1 raw-f32
// prefetch of next s-iter's K+V stays in flight across the barrier pair.
__global__ __launch_bounds__(256, 2) void kernelA(const float* __restrict__ keys,
                                                  const float* __restrict__ values,
                                                  const float* __restrict__ features,
                                                  float* __restrict__ kvp,
                                                  float* __restrict__ ksum_p) {
    __shared__ ushort_t FB[16384];  // 32 KB : F B-frags
    __shared__ ushort_t PA[8192];   // 16 KB : phi^T A-frags (64 l x 128 m)
    __shared__ ushort_t VB[8192];   // 16 KB : V B-frags   (64 l x 128 v)

    const int tid = threadIdx.x;
    const int chunk = blockIdx.x, b = blockIdx.y;
    const int w = tid >> 6, lane = tid & 63;
    const int qa = lane >> 4, ra = lane & 15;
    const int l0 = chunk * LT;
    const int lrel = w * 16 + ra;

    // per-it V addressing (invariant part)
    int v_off[4];
#pragma unroll
    for (int it = 0; it < 4; ++it) {
        int bid = tid + it * 256;
        int v  = ((bid >> 6) & 7) * 16 + (bid & 15);
        int lr = (bid >> 9) * 32 + ((bid >> 4) & 3) * 8;
        v_off[it] = (b * D_ + v) * L_ + lr;
    }
    const float* kcol = keys + (size_t)b * D_ * L_;

    // ---- issue s=0 V + K loads first (raw f32, converted at use)
    float4v vf[4][2];
    float   fk[4][8];
#pragma unroll
    for (int it = 0; it < 4; ++it) {
        const float* vp = values + v_off[it] + l0;
        vf[it][0] = *(const float4v*)vp;
        vf[it][1] = *(const float4v*)(vp + 4);
    }
#pragma unroll
    for (int kt = 0; kt < 4; ++kt)
#pragma unroll
        for (int j = 0; j < 8; ++j)
            fk[kt][j] = kcol[(size_t)(kt * 32 + qa * 8 + j) * L_ + l0 + lrel];

    stage_features(features, FB, tid);

    float4v acc2[2][8];
    float   ksum_acc[8];
#pragma unroll
    for (int i = 0; i < 2; ++i)
#pragma unroll
        for (int nt = 0; nt < 8; ++nt) acc2[i][nt] = (float4v){0.f, 0.f, 0.f, 0.f};
#pragma unroll
    for (int nt = 0; nt < 8; ++nt) ksum_acc[nt] = 0.f;

#pragma unroll
    for (int s = 0; s < 4; ++s) {
        const int ls = l0 + s * SL;
        BAR_LDS();  // prev GEMM2 done; PA/VB reusable; (s=0: FB visible). VMEM stays in flight.

        // ---- write V subtile to LDS (consumes vf)
#pragma unroll
        for (int it = 0; it < 4; ++it) {
            ushort8 u;
            u[0] = f2bf(vf[it][0].x); u[1] = f2bf(vf[it][0].y);
            u[2] = f2bf(vf[it][0].z); u[3] = f2bf(vf[it][0].w);
            u[4] = f2bf(vf[it][1].x); u[5] = f2bf(vf[it][1].y);
            u[6] = f2bf(vf[it][1].z); u[7] = f2bf(vf[it][1].w);
            *(ushort8*)(VB + (tid + it * 256) * 8) = u;
        }

        // ---- convert K (consumes fk)
        ushort8 af[4];
#pragma unroll
        for (int kt = 0; kt < 4; ++kt) {
            ushort8 a;
#pragma unroll
            for (int j = 0; j < 8; ++j) a[j] = f2bf(fk[kt][j]);
            af[kt] = a;
        }

        // ---- prefetch next s-iter's V + K (in flight across GEMM1+epilogue+GEMM2+barriers)
        if (s < 3) {
#pragma unroll
            for (int it = 0; it < 4; ++it) {
                const float* vp = values + v_off[it] + ls + SL;
                vf[it][0] = *(const float4v*)vp;
                vf[it][1] = *(const float4v*)(vp + 4);
            }
#pragma unroll
            for (int kt = 0; kt < 4; ++kt)
#pragma unroll
                for (int j = 0; j < 8; ++j)
                    fk[kt][j] = kcol[(size_t)(kt * 32 + qa * 8 + j) * L_ + ls + SL + lrel];
        }

        // ---- GEMM1: phi(64 x 128) = K_sub^T @ F; wave w owns l-rows [w*16, w*16+16)
        float4v acc1[8];
#pragma unroll
        for (int nt = 0; nt < 8; ++nt) acc1[nt] = (float4v){0.f, 0.f, 0.f, 0.f};
#pragma unroll
        for (int kt = 0; kt < 4; ++kt)
#pragma unroll
            for (int nt = 0; nt < 8; ++nt)
                acc1[nt] = mfma16(af[kt], *(const ushort8*)(FB + ((kt * 8 + nt) * 64 + lane) * 8),
                                  acc1[nt]);

        // ---- epilogue: relu*scale, ksum accumulate, write phi^T into A-frag layout
        {
            const int qc = qa, cc = ra;
            const int kt2 = w >> 1;
            const int qa2 = (w & 1) * 2 + (qc >> 1);
            const int jb  = (qc & 1) * 4;
#pragma unroll
            for (int nt = 0; nt < 8; ++nt) {
                float4v p = acc1[nt];
                p.x = fmaxf(p.x, 0.f) * PHI_SCALE;
                p.y = fmaxf(p.y, 0.f) * PHI_SCALE;
                p.z = fmaxf(p.z, 0.f) * PHI_SCALE;
                p.w = fmaxf(p.w, 0.f) * PHI_SCALE;
                ksum_acc[nt] += p.x + p.y + p.z + p.w;
                ushort4v u4 = {f2bf(p.x), f2bf(p.y), f2bf(p.z), f2bf(p.w)};
                *(ushort4v*)(PA + (((kt2 * 8 + nt) * 64 + qa2 * 16 + cc) * 8 + jb)) = u4;
            }
        }
        BAR_LDS();  // PA + VB visible; prefetch loads still in flight

        // ---- GEMM2: kv[m][v] += phi^T (128 x 64) @ V (64 x 128); wave w owns m [32w,32w+32)
#pragma unroll
        for (int kt2 = 0; kt2 < 2; ++kt2) {
            ushort8 a0 = *(const ushort8*)(PA + ((kt2 * 8 + 2 * w + 0) * 64 + lane) * 8);
            ushort8 a1 = *(const ushort8*)(PA + ((kt2 * 8 + 2 * w + 1) * 64 + lane) * 8);
#pragma unroll
            for (int nt = 0; nt < 8; ++nt) {
                ushort8 bb = *(const ushort8*)(VB + ((kt2 * 8 + nt) * 64 + lane) * 8);
                acc2[0][nt] = mfma16(a0, bb, acc2[0][nt]);
                acc2[1][nt] = mfma16(a1, bb, acc2[1][nt]);
            }
        }
    }

    // ---- write kv partials (f32) and ksum partials
    float* kvpb = kvp + ((size_t)(b * NCHUNK + chunk)) * M_ * D_;
    const int qc = lane >> 4, cc = lane & 15;
#pragma unroll
    for (int mi = 0; mi < 2; ++mi)
#pragma unroll
        for (int nt = 0; nt < 8; ++nt) {
            float4v p = acc2[mi][nt];
            int m0 = w * 32 + mi * 16 + qc * 4;
            int v  = nt * 16 + cc;
            kvpb[(m0 + 0) * D_ + v] = p.x;
            kvpb[(m0 + 1) * D_ + v] = p.y;
            kvpb[(m0 + 2) * D_ + v] = p.z;
            kvpb[(m0 + 3) * D_ + v] = p.w;
        }
    float* ksb = ksum_p + ((size_t)((b * NCHUNK + chunk) * 4 + w)) * M_;
#pragma unroll
    for (int nt = 0; nt < 8; ++nt) {
        float sv = ksum_acc[nt];
        sv += __shfl_xor(sv, 16);
        sv += __shfl_xor(sv, 32);
        if (qc == 0) ksb[nt * 16 + cc] = sv;
    }
}

// Kernel R: reduce 32 chunk-partials -> kv_final (bf16 B-frag blocks) + ksum_final f32 [b][128]
__global__ __launch_bounds__(256) void kernelR(const float* __restrict__ kvp,
                                               const float* __restrict__ ksum_p,
                                               ushort_t* __restrict__ kv_final,
                                               float* __restrict__ ksum_final) {
    if (blockIdx.x < 256) {
        int h = blockIdx.x >> 7;                         // j-half 0/1
        int t = (blockIdx.x & 127) * 256 + threadIdx.x;  // slot 0..32767
        int b = t >> 11, bid = t & 2047;
        int cb = bid & 15, qb = (bid >> 4) & 3, nt = (bid >> 6) & 7, kt = bid >> 9;
        int v  = nt * 16 + cb;
        int m0 = kt * 32 + qb * 8 + h * 4;
        const float* base = kvp + ((size_t)b * NCHUNK) * (M_ * D_) + m0 * D_ + v;
        float s0 = 0.f, s1 = 0.f, s2 = 0.f, s3 = 0.f;
#pragma unroll 4
        for (int c = 0; c < NCHUNK; ++c) {
            const float* p = base + (size_t)c * (M_ * D_);
            s0 += p[0 * D_]; s1 += p[1 * D_]; s2 += p[2 * D_]; s3 += p[3 * D_];
        }
        ushort4v u = {f2bf(s0), f2bf(s1), f2bf(s2), f2bf(s3)};
        *(ushort4v*)(kv_final + (size_t)t * 8 + h * 4) = u;
    } else {
        int t2 = (blockIdx.x - 256) * 256 + threadIdx.x;  // 0..2047
        int b = t2 >> 7, m = t2 & 127;
        const float* p = ksum_p + ((size_t)b * NCHUNK) * 4 * M_ + m;
        float sacc = 0.f;
#pragma unroll 8
        for (int cw = 0; cw < NCHUNK * 4; ++cw) sacc += p[cw * M_];
        ksum_final[t2] = sacc;
    }
}

// Kernel QC (fused): phi_q = relu(Q^T F)*s ; out = (phi_q @ kv)/(phi_q . ksum)
// LDS = 32+32+8 = 72 KB -> 2 blocks/CU. PQA halved: nt 0..3 -> GEMM2 kt 0,1 -> nt 4..7 ->
// kt 2,3 (per-wave-private, in-wave ordering only). Raw-f32 Q prefetch pipelines s-iters.
__global__ __launch_bounds__(256, 2) void kernelQC(const float* __restrict__ queries,
                                                   const float* __restrict__ features,
                                                   const ushort_t* __restrict__ kv_final,
                                                   const float* __restrict__ ksum_final,
                                                   float* __restrict__ out) {
    __shared__ ushort_t FB[16384];   // 32 KB : F B-frags
    __shared__ ushort_t KVB[16384];  // 32 KB : kv B-frags (B[k=m][n=v])
    __shared__ ushort_t PQA[4096];   //  8 KB : phi_q A-frags, per-wave halves

    const int tid = threadIdx.x;
    const int chunk = blockIdx.x, b = blockIdx.y;
    const int w = tid >> 6, lane = tid & 63;
    const int qa = lane >> 4, ra = lane & 15;
    const int qc = qa, cc = ra;
    const int lrel = w * 16 + ra;

    // ---- issue s=0 Q loads first (raw f32)
    const float* qbase = queries + (size_t)b * D_ * L_;
    float fq[4][8];
#pragma unroll
    for (int kt = 0; kt < 4; ++kt)
#pragma unroll
        for (int j = 0; j < 8; ++j)
            fq[kt][j] = qbase[(size_t)(kt * 32 + qa * 8 + j) * L_ + chunk * LT + lrel];

    stage_features(features, FB, tid);
#pragma unroll
    for (int it = 0; it < 8; ++it) {
        int bid = tid + it * 256;  // 0..2047
        *(ushort8*)(KVB + bid * 8) =
            *(const ushort8*)(kv_final + ((size_t)b * 2048 + bid) * 8);
    }
    float ks[8];
#pragma unroll
    for (int nt = 0; nt < 8; ++nt) ks[nt] = ksum_final[b * M_ + nt * 16 + ra];
    __syncthreads();

#pragma unroll
    for (int s = 0; s < 4; ++s) {
        const int ls = chunk * LT + s * SL;

        // ---- convert current Q (consumes fq)
        ushort8 af[4];
#pragma unroll
        for (int kt = 0; kt < 4; ++kt) {
            ushort8 a;
#pragma unroll
            for (int j = 0; j < 8; ++j) a[j] = f2bf(fq[kt][j]);
            af[kt] = a;
        }
        // ---- prefetch next s-iter's Q (no barriers in the loop -> stays in flight)
        if (s < 3) {
#pragma unroll
            for (int kt = 0; kt < 4; ++kt)
#pragma unroll
                for (int j = 0; j < 8; ++j)
                    fq[kt][j] = qbase[(size_t)(kt * 32 + qa * 8 + j) * L_ + ls + SL + lrel];
        }

        // ---- GEMM1: phi_q(64 x 128) = Q_sub^T @ F
        float4v acc1[8];
#pragma unroll
        for (int nt = 0; nt < 8; ++nt) acc1[nt] = (float4v){0.f, 0.f, 0.f, 0.f};
#pragma unroll
        for (int kt = 0; kt < 4; ++kt)
#pragma unroll
            for (int nt = 0; nt < 8; ++nt)
                acc1[nt] = mfma16(af[kt], *(const ushort8*)(FB + ((kt * 8 + nt) * 64 + lane) * 8),
                                  acc1[nt]);

        // ---- relu*scale + f32 denominator dot (ksum in regs)
        float dp0 = 0.f, dp1 = 0.f, dp2 = 0.f, dp3 = 0.f;
#pragma unroll
        for (int nt = 0; nt < 8; ++nt) {
            float4v p = acc1[nt];
            p.x = fmaxf(p.x, 0.f) * PHI_SCALE;
            p.y = fmaxf(p.y, 0.f) * PHI_SCALE;
            p.z = fmaxf(p.z, 0.f) * PHI_SCALE;
            p.w = fmaxf(p.w, 0.f) * PHI_SCALE;
            dp0 += p.x * ks[nt]; dp1 += p.y * ks[nt];
            dp2 += p.z * ks[nt]; dp3 += p.w * ks[nt];
            acc1[nt] = p;
        }
#pragma unroll
        for (int off = 1; off < 16; off <<= 1) {
            dp0 += __shfl_xor(dp0, off);
            dp1 += __shfl_xor(dp1, off);
            dp2 += __shfl_xor(dp2, off);
            dp3 += __shfl_xor(dp3, off);
        }
        float i0 = 1.f / dp0, i1 = 1.f / dp1, i2 = 1.f / dp2, i3 = 1.f / dp3;

        // ---- GEMM2 in two m-halves through the 8KB per-wave PQA
        float4v acc[8];
#pragma unroll
        for (int nt = 0; nt < 8; ++nt) acc[nt] = (float4v){0.f, 0.f, 0.f, 0.f};
#pragma unroll
        for (int h = 0; h < 2; ++h) {
#pragma unroll
            for (int nt = 4 * h; nt < 4 * h + 4; ++nt) {
                float4v p = acc1[nt];
                int baseu = ((((nt >> 1) & 1) * 4 + w) * 64 +
                             ((nt & 1) * 2 + (cc >> 3)) * 16 + qc * 4) * 8 + (cc & 7);
                PQA[baseu +  0] = f2bf(p.x);
                PQA[baseu +  8] = f2bf(p.y);
                PQA[baseu + 16] = f2bf(p.z);
                PQA[baseu + 24] = f2bf(p.w);
            }
#pragma unroll
            for (int kt = 2 * h; kt < 2 * h + 2; ++kt) {
                ushort8 a = *(const ushort8*)(PQA + (((kt & 1) * 4 + w) * 64 + lane) * 8);
#pragma unroll
                for (int nt2 = 0; nt2 < 8; ++nt2)
                    acc[nt2] = mfma16(a, *(const ushort8*)(KVB + ((kt * 8 + nt2) * 64 + lane) * 8),
                                      acc[nt2]);
            }
        }

        // ---- scale by 1/denom and store
        const int lbase = ls + w * 16 + qc * 4;
#pragma unroll
        for (int nt = 0; nt < 8; ++nt) {
            float4v o = acc[nt];
            o.x *= i0; o.y *= i1; o.z *= i2; o.w *= i3;
            *(float4v*)(out + ((size_t)(b * D_ + nt * 16 + cc)) * L_ + lbase) = o;
        }
    }
}

extern "C" void kernel_launch(void* const* d_in, const int* in_sizes, int n_in,
                              void* d_out, int out_size, void* d_ws, size_t ws_size,
                              hipStream_t stream) {
    (void)in_sizes; (void)n_in; (void)out_size; (void)ws_size;
    const float* keys     = (const float*)d_in[0];
    const float* values   = (const float*)d_in[1];
    const float* queries  = (const float*)d_in[2];
    const float* features = (const float*)d_in[3];
    float* out = (float*)d_out;

    // workspace partition (total ~35.1 MB)
    char* ws = (char*)d_ws;
    float*    kvp        = (float*)ws;                        // 16*32*128*128*4 = 33,554,432
    float*    ksum_p     = (float*)(ws + 33554432);           // 16*32*4*128*4   =  1,048,576
    ushort_t* kv_final   = (ushort_t*)(ws + 34603008);        // 16*2048*8*2     =    524,288
    float*    ksum_final = (float*)(ws + 35127296);           // 16*128*4        =      8,192

    dim3 grid(NCHUNK, B_);
    kernelA<<<grid, 256, 0, stream>>>(keys, values, features, kvp, ksum_p);
    kernelR<<<264, 256, 0, stream>>>(kvp, ksum_p, kv_final, ksum_final);
    kernelQC<<<grid, 256, 0, stream>>>(queries, features, kv_final, ksum_final, out);
}